// Round 1
// baseline (154.555 us; speedup 1.0000x reference)
//
#include <hip/hip_runtime.h>
#include <math.h>

// Problem constants
#define BSZ   512
#define XD    768
#define YD    128
#define H2D   512

// ---------------------------------------------------------------------------
// Kernel C: column moments of y (fp64) + zero the fp64 accumulators.
// y: (512,128). Sy[d] = sum_i y[i,d]; Sy2[d] = sum_i y[i,d]^2.
// 256 threads: d = t&127, half = t>>7 (each sums 256 rows), LDS combine.
// ---------------------------------------------------------------------------
__global__ __launch_bounds__(256) void ysum_kernel(
    const float* __restrict__ y, double* __restrict__ Sy,
    double* __restrict__ Sy2, double* __restrict__ accum)
{
    const int t = threadIdx.x;
    const int d = t & 127;
    const int h = t >> 7;
    double s = 0.0, s2 = 0.0;
    for (int i = h * 256; i < h * 256 + 256; ++i) {
        double v = (double)y[i * YD + d];
        s += v; s2 += v * v;
    }
    __shared__ double sh[2][128];
    __shared__ double sh2[2][128];
    sh[h][d] = s; sh2[h][d] = s2;
    __syncthreads();
    if (t < 128) {
        Sy[d]  = sh[0][d]  + sh[1][d];
        Sy2[d] = sh2[0][d] + sh2[1][d];
    } else if (t == 128) {
        accum[0] = 0.0;
    } else if (t == 129) {
        accum[1] = 0.0;
    }
}

// ---------------------------------------------------------------------------
// Kernel A: layer 1 — H = relu(x @ W1 + b1) for both mu and lv branches.
// x: (512,768), W1: (768,512), H: (512,512).
// Tiles: 32(M) x 64(N) x 16(K); 256 threads; each thread 2x4 outputs.
// Grid (16, 8, 2) = 256 blocks -> one per CU.
// ---------------------------------------------------------------------------
__global__ __launch_bounds__(256) void layer1_kernel(
    const float* __restrict__ x,
    const float* __restrict__ w1_mu, const float* __restrict__ b1_mu,
    const float* __restrict__ w1_lv, const float* __restrict__ b1_lv,
    float* __restrict__ h_mu, float* __restrict__ h_lv)
{
    const int which = blockIdx.z;
    const float* __restrict__ W    = which ? w1_lv : w1_mu;
    const float* __restrict__ bias = which ? b1_lv : b1_mu;
    float* __restrict__ H          = which ? h_lv  : h_mu;

    __shared__ float As[16][33];   // [k][m], +1 pad breaks store conflicts
    __shared__ float Bs[16][64];   // [k][n]

    const int t  = threadIdx.x;
    const int m0 = blockIdx.x * 32;
    const int n0 = blockIdx.y * 64;
    const int tx = t & 15;         // n-group (4 cols each)
    const int ty = t >> 4;         // m-group (2 rows each)

    float acc[2][4] = {{0.f,0.f,0.f,0.f},{0.f,0.f,0.f,0.f}};

    for (int k0 = 0; k0 < XD; k0 += 16) {
        // A tile: 32 rows x 16 k, 128 float4 loads by threads < 128,
        // stored transposed [k][m].
        if (t < 128) {
            const int row = t >> 2;
            const int kq  = (t & 3) << 2;
            const float4 a = *(const float4*)&x[(m0 + row) * XD + k0 + kq];
            As[kq + 0][row] = a.x; As[kq + 1][row] = a.y;
            As[kq + 2][row] = a.z; As[kq + 3][row] = a.w;
        }
        // B tile: 16 k x 64 n = 256 float4, one per thread.
        {
            const int kk = t >> 4;
            const int nq = (t & 15) << 2;
            *(float4*)&Bs[kk][nq] = *(const float4*)&W[(k0 + kk) * H2D + n0 + nq];
        }
        __syncthreads();
        #pragma unroll
        for (int k = 0; k < 16; ++k) {
            const float a0 = As[k][ty * 2 + 0];
            const float a1 = As[k][ty * 2 + 1];
            const float4 b = *(const float4*)&Bs[k][tx * 4];
            acc[0][0] += a0 * b.x; acc[0][1] += a0 * b.y;
            acc[0][2] += a0 * b.z; acc[0][3] += a0 * b.w;
            acc[1][0] += a1 * b.x; acc[1][1] += a1 * b.y;
            acc[1][2] += a1 * b.z; acc[1][3] += a1 * b.w;
        }
        __syncthreads();
    }

    const int n = n0 + tx * 4;
    const float4 bi = *(const float4*)&bias[n];
    #pragma unroll
    for (int r = 0; r < 2; ++r) {
        const int m = m0 + ty * 2 + r;
        float4 o;
        o.x = fmaxf(acc[r][0] + bi.x, 0.f);
        o.y = fmaxf(acc[r][1] + bi.y, 0.f);
        o.z = fmaxf(acc[r][2] + bi.z, 0.f);
        o.w = fmaxf(acc[r][3] + bi.w, 0.f);
        *(float4*)&H[m * H2D + n] = o;
    }
}

// ---------------------------------------------------------------------------
// Kernel B: layer 2 — mu = H_mu @ W2_mu + b2_mu ; lv = tanh(H_lv @ W2_lv + b2_lv)
// H: (512,512), W2: (512,128), out: (512,128).
// Tiles: 32(M) x 32(N) x 16(K); 256 threads; each thread 2x2 outputs.
// Grid (16, 4, 2) = 128 blocks.
// ---------------------------------------------------------------------------
__global__ __launch_bounds__(256) void layer2_kernel(
    const float* __restrict__ h_mu, const float* __restrict__ h_lv,
    const float* __restrict__ w2_mu, const float* __restrict__ b2_mu,
    const float* __restrict__ w2_lv, const float* __restrict__ b2_lv,
    float* __restrict__ mu, float* __restrict__ lv)
{
    const int which = blockIdx.z;
    const float* __restrict__ A    = which ? h_lv  : h_mu;
    const float* __restrict__ W    = which ? w2_lv : w2_mu;
    const float* __restrict__ bias = which ? b2_lv : b2_mu;
    float* __restrict__ O          = which ? lv    : mu;

    __shared__ float As[16][33];
    __shared__ float Bs[16][32];

    const int t  = threadIdx.x;
    const int m0 = blockIdx.x * 32;
    const int n0 = blockIdx.y * 32;
    const int tx = t & 15;
    const int ty = t >> 4;

    float acc00 = 0.f, acc01 = 0.f, acc10 = 0.f, acc11 = 0.f;

    for (int k0 = 0; k0 < H2D; k0 += 16) {
        if (t < 128) {
            // A tile: 32 rows x 16 k, transposed store.
            const int row = t >> 2;
            const int kq  = (t & 3) << 2;
            const float4 a = *(const float4*)&A[(m0 + row) * H2D + k0 + kq];
            As[kq + 0][row] = a.x; As[kq + 1][row] = a.y;
            As[kq + 2][row] = a.z; As[kq + 3][row] = a.w;
        } else {
            // B tile: 16 k x 32 n = 128 float4 by threads 128..255.
            const int u  = t - 128;
            const int kk = u >> 3;
            const int nq = (u & 7) << 2;
            *(float4*)&Bs[kk][nq] = *(const float4*)&W[(k0 + kk) * YD + n0 + nq];
        }
        __syncthreads();
        #pragma unroll
        for (int k = 0; k < 16; ++k) {
            const float a0 = As[k][ty * 2 + 0];
            const float a1 = As[k][ty * 2 + 1];
            const float b0 = Bs[k][tx * 2 + 0];
            const float b1 = Bs[k][tx * 2 + 1];
            acc00 += a0 * b0; acc01 += a0 * b1;
            acc10 += a1 * b0; acc11 += a1 * b1;
        }
        __syncthreads();
    }

    const int n = n0 + tx * 2;
    const float bi0 = bias[n], bi1 = bias[n + 1];
    #pragma unroll
    for (int r = 0; r < 2; ++r) {
        const int m = m0 + ty * 2 + r;
        float v0 = (r ? acc10 : acc00) + bi0;
        float v1 = (r ? acc11 : acc01) + bi1;
        if (which) { v0 = tanhf(v0); v1 = tanhf(v1); }
        *(float2*)&O[m * YD + n] = make_float2(v0, v1);
    }
}

// ---------------------------------------------------------------------------
// Kernel D: fp64 reduction over (512,128):
//   pos += -0.5*(mu-y)^2*iv - 0.5*lv
//   ap  += iv*(-0.5*Sy2[d] + mu*Sy[d] - 0.5*B*mu^2) - 0.5*B*lv
// ---------------------------------------------------------------------------
__global__ __launch_bounds__(256) void reduce_kernel(
    const float* __restrict__ mu, const float* __restrict__ lv,
    const float* __restrict__ y,
    const double* __restrict__ Sy, const double* __restrict__ Sy2,
    double* __restrict__ accum)
{
    const double Bd = (double)BSZ;
    double pos = 0.0, ap = 0.0;
    for (int idx = blockIdx.x * 256 + threadIdx.x; idx < BSZ * YD;
         idx += gridDim.x * 256) {
        const int d = idx & (YD - 1);
        const double m  = (double)mu[idx];
        const double l  = (double)lv[idx];
        const double yv = (double)y[idx];
        const double iv = exp(-l);
        const double dm = m - yv;
        pos += -0.5 * dm * dm * iv - 0.5 * l;
        ap  += iv * (-0.5 * Sy2[d] + m * Sy[d] - 0.5 * Bd * m * m) - 0.5 * Bd * l;
    }
    // wave64 shuffle reduction
    #pragma unroll
    for (int off = 32; off > 0; off >>= 1) {
        pos += __shfl_down(pos, off);
        ap  += __shfl_down(ap, off);
    }
    __shared__ double sp[4];
    __shared__ double sa[4];
    const int lane = threadIdx.x & 63;
    const int wv   = threadIdx.x >> 6;
    if (lane == 0) { sp[wv] = pos; sa[wv] = ap; }
    __syncthreads();
    if (threadIdx.x == 0) {
        atomicAdd(&accum[0], sp[0] + sp[1] + sp[2] + sp[3]);
        atomicAdd(&accum[1], sa[0] + sa[1] + sa[2] + sa[3]);
    }
}

// ---------------------------------------------------------------------------
// Kernel E: finalize. out = posSum/B - apSum/B^2 - log1p(exp(-20)/(B-1))
// ---------------------------------------------------------------------------
__global__ void finalize_kernel(const double* __restrict__ accum,
                                float* __restrict__ out)
{
    if (threadIdx.x == 0) {
        const double C = log1p(exp(-20.0) / (double)(BSZ - 1));
        const double res = accum[0] / (double)BSZ
                         - accum[1] / ((double)BSZ * (double)BSZ) - C;
        out[0] = (float)res;
    }
}

extern "C" void kernel_launch(void* const* d_in, const int* in_sizes, int n_in,
                              void* d_out, int out_size, void* d_ws, size_t ws_size,
                              hipStream_t stream) {
    const float* x     = (const float*)d_in[0];
    const float* y     = (const float*)d_in[1];
    const float* w1_mu = (const float*)d_in[2];
    const float* b1_mu = (const float*)d_in[3];
    const float* w2_mu = (const float*)d_in[4];
    const float* b2_mu = (const float*)d_in[5];
    const float* w1_lv = (const float*)d_in[6];
    const float* b1_lv = (const float*)d_in[7];
    const float* w2_lv = (const float*)d_in[8];
    const float* b2_lv = (const float*)d_in[9];

    char* ws = (char*)d_ws;
    float*  h_mu  = (float*)(ws);                                   // 1 MB
    float*  h_lv  = (float*)(ws + (size_t)BSZ * H2D * 4);           // 1 MB
    float*  mu    = (float*)(ws + (size_t)2 * BSZ * H2D * 4);       // 256 KB
    float*  lv    = (float*)(ws + (size_t)2 * BSZ * H2D * 4
                                + (size_t)BSZ * YD * 4);            // 256 KB
    double* Sy    = (double*)(ws + (size_t)2 * BSZ * H2D * 4
                                 + (size_t)2 * BSZ * YD * 4);       // 1 KB
    double* Sy2   = Sy + YD;                                        // 1 KB
    double* accum = Sy2 + YD;                                       // 16 B

    ysum_kernel<<<1, 256, 0, stream>>>(y, Sy, Sy2, accum);
    layer1_kernel<<<dim3(16, 8, 2), 256, 0, stream>>>(
        x, w1_mu, b1_mu, w1_lv, b1_lv, h_mu, h_lv);
    layer2_kernel<<<dim3(16, 4, 2), 256, 0, stream>>>(
        h_mu, h_lv, w2_mu, b2_mu, w2_lv, b2_lv, mu, lv);
    reduce_kernel<<<128, 256, 0, stream>>>(mu, lv, y, Sy, Sy2, accum);
    finalize_kernel<<<1, 64, 0, stream>>>(accum, (float*)d_out);
}

// Round 2
// 117.632 us; speedup vs baseline: 1.3139x; 1.3139x over previous
//
#include <hip/hip_runtime.h>
#include <math.h>

// Problem constants
#define BSZ   512
#define XD    768
#define YD    128
#define H2D   512

// ---------------------------------------------------------------------------
// ysum: Sy[d] = sum_i y[i,d], Sy2[d] = sum_i y[i,d]^2 (fp32 partials, fp64
// combine). Grid 4 blocks x 512 threads; block b owns dims b*32..b*32+31.
// Thread (dl,g): dl = t&31 (dim), g = t>>5 (row group of 32). Also zeroes
// the fp64 accumulators (block 0).
// ---------------------------------------------------------------------------
__global__ __launch_bounds__(512) void ysum_kernel(
    const float* __restrict__ y, double* __restrict__ Sy,
    double* __restrict__ Sy2, double* __restrict__ accum)
{
    const int t  = threadIdx.x;
    const int dl = t & 31;
    const int g  = t >> 5;                 // 0..15
    const int d  = blockIdx.x * 32 + dl;

    float s = 0.f, s2 = 0.f;
    for (int i = g * 32; i < g * 32 + 32; ++i) {
        const float v = y[i * YD + d];
        s += v; s2 += v * v;
    }
    __shared__ float sh[16][33];
    __shared__ float sh2[16][33];
    sh[g][dl] = s; sh2[g][dl] = s2;
    __syncthreads();
    if (t < 32) {
        double S = 0.0, S2 = 0.0;
        #pragma unroll
        for (int gg = 0; gg < 16; ++gg) { S += (double)sh[gg][t]; S2 += (double)sh2[gg][t]; }
        Sy[blockIdx.x * 32 + t]  = S;
        Sy2[blockIdx.x * 32 + t] = S2;
    } else if (blockIdx.x == 0 && t == 32) {
        accum[0] = 0.0;
    } else if (blockIdx.x == 0 && t == 33) {
        accum[1] = 0.0;
    }
}

// ---------------------------------------------------------------------------
// layer1: H = relu(x @ W1 + b1), both branches.
// x:(512,768) W1:(768,512) H:(512,512).
// Tile 32x32, grid (16,16,2) = 512 blocks -> 2 blocks/CU, 8 waves/CU
// (independent barriers between the two co-resident blocks hide the drain).
// LDS layouts are k-contiguous (As[m][k], Bs[n][k], stride 68 = 16B aligned,
// worst bank aliasing 2-way = free) so the inner loop is 4x ds_read_b128
// per 4 k-steps feeding 16 FMAs (4 accumulators, 2m x 2n per thread,
// m in {ty, ty+16}, n in {tx, tx+16}).
// ---------------------------------------------------------------------------
__global__ __launch_bounds__(256, 2) void layer1_kernel(
    const float* __restrict__ x,
    const float* __restrict__ w1_mu, const float* __restrict__ b1_mu,
    const float* __restrict__ w1_lv, const float* __restrict__ b1_lv,
    float* __restrict__ h_mu, float* __restrict__ h_lv)
{
    const int which = blockIdx.z;
    const float* __restrict__ W    = which ? w1_lv : w1_mu;
    const float* __restrict__ bias = which ? b1_lv : b1_mu;
    float* __restrict__ H          = which ? h_lv  : h_mu;

    __shared__ float As[32][68];   // [m][k]
    __shared__ float Bs[32][68];   // [n][k] (transposed at stage time)

    const int t  = threadIdx.x;
    const int m0 = blockIdx.x * 32;
    const int n0 = blockIdx.y * 32;
    const int tx = t & 15;
    const int ty = t >> 4;

    // staging thread mapping
    const int ar = t >> 3;          // A row 0..31
    const int ak = (t & 7) * 8;     // A k-offset (2 float4)
    const int bk = t >> 2;          // B k-row 0..63
    const int bn = (t & 3) * 8;     // B n-offset (2 float4)

    float acc00 = 0.f, acc01 = 0.f, acc10 = 0.f, acc11 = 0.f;

    for (int k0 = 0; k0 < XD; k0 += 64) {
        const float4 a_lo = *(const float4*)&x[(m0 + ar) * XD + k0 + ak];
        const float4 a_hi = *(const float4*)&x[(m0 + ar) * XD + k0 + ak + 4];
        const float4 w_lo = *(const float4*)&W[(k0 + bk) * H2D + n0 + bn];
        const float4 w_hi = *(const float4*)&W[(k0 + bk) * H2D + n0 + bn + 4];
        __syncthreads();   // previous iteration's LDS reads complete
        *(float4*)&As[ar][ak]     = a_lo;
        *(float4*)&As[ar][ak + 4] = a_hi;
        Bs[bn + 0][bk] = w_lo.x; Bs[bn + 1][bk] = w_lo.y;
        Bs[bn + 2][bk] = w_lo.z; Bs[bn + 3][bk] = w_lo.w;
        Bs[bn + 4][bk] = w_hi.x; Bs[bn + 5][bk] = w_hi.y;
        Bs[bn + 6][bk] = w_hi.z; Bs[bn + 7][bk] = w_hi.w;
        __syncthreads();
        #pragma unroll
        for (int k = 0; k < 64; k += 4) {
            const float4 a0 = *(const float4*)&As[ty][k];
            const float4 a1 = *(const float4*)&As[ty + 16][k];
            const float4 b0 = *(const float4*)&Bs[tx][k];
            const float4 b1 = *(const float4*)&Bs[tx + 16][k];
            acc00 += a0.x*b0.x; acc00 += a0.y*b0.y; acc00 += a0.z*b0.z; acc00 += a0.w*b0.w;
            acc01 += a0.x*b1.x; acc01 += a0.y*b1.y; acc01 += a0.z*b1.z; acc01 += a0.w*b1.w;
            acc10 += a1.x*b0.x; acc10 += a1.y*b0.y; acc10 += a1.z*b0.z; acc10 += a1.w*b0.w;
            acc11 += a1.x*b1.x; acc11 += a1.y*b1.y; acc11 += a1.z*b1.z; acc11 += a1.w*b1.w;
        }
    }

    const int na = n0 + tx, nb = n0 + tx + 16;
    const float ba = bias[na], bb = bias[nb];
    H[(m0 + ty)      * H2D + na] = fmaxf(acc00 + ba, 0.f);
    H[(m0 + ty)      * H2D + nb] = fmaxf(acc01 + bb, 0.f);
    H[(m0 + ty + 16) * H2D + na] = fmaxf(acc10 + ba, 0.f);
    H[(m0 + ty + 16) * H2D + nb] = fmaxf(acc11 + bb, 0.f);
}

// ---------------------------------------------------------------------------
// layer2p: split-K partials of H @ W2 (NO bias, NO tanh — both applied in
// reduce). H:(512,512) W2:(512,128). Grid (16,4,8): z = branch*4 + kz,
// each block does K-chunk kz*128..+128. Partials land in
// part[(branch*4+kz)][512][128] — no atomics, no init required.
// Same tile/LDS template as layer1.
// ---------------------------------------------------------------------------
__global__ __launch_bounds__(256, 2) void layer2p_kernel(
    const float* __restrict__ h_mu, const float* __restrict__ h_lv,
    const float* __restrict__ w2_mu, const float* __restrict__ w2_lv,
    float* __restrict__ part)
{
    const int branch = blockIdx.z >> 2;
    const int kz     = blockIdx.z & 3;
    const float* __restrict__ A = branch ? h_lv  : h_mu;
    const float* __restrict__ W = branch ? w2_lv : w2_mu;
    float* __restrict__ out = part + (size_t)blockIdx.z * (BSZ * YD);

    __shared__ float As[32][68];
    __shared__ float Bs[32][68];

    const int t  = threadIdx.x;
    const int m0 = blockIdx.x * 32;
    const int n0 = blockIdx.y * 32;
    const int tx = t & 15;
    const int ty = t >> 4;

    const int ar = t >> 3;
    const int ak = (t & 7) * 8;
    const int bk = t >> 2;
    const int bn = (t & 3) * 8;

    float acc00 = 0.f, acc01 = 0.f, acc10 = 0.f, acc11 = 0.f;

    const int kbase = kz * 128;
    for (int k0 = kbase; k0 < kbase + 128; k0 += 64) {
        const float4 a_lo = *(const float4*)&A[(m0 + ar) * H2D + k0 + ak];
        const float4 a_hi = *(const float4*)&A[(m0 + ar) * H2D + k0 + ak + 4];
        const float4 w_lo = *(const float4*)&W[(k0 + bk) * YD + n0 + bn];
        const float4 w_hi = *(const float4*)&W[(k0 + bk) * YD + n0 + bn + 4];
        __syncthreads();
        *(float4*)&As[ar][ak]     = a_lo;
        *(float4*)&As[ar][ak + 4] = a_hi;
        Bs[bn + 0][bk] = w_lo.x; Bs[bn + 1][bk] = w_lo.y;
        Bs[bn + 2][bk] = w_lo.z; Bs[bn + 3][bk] = w_lo.w;
        Bs[bn + 4][bk] = w_hi.x; Bs[bn + 5][bk] = w_hi.y;
        Bs[bn + 6][bk] = w_hi.z; Bs[bn + 7][bk] = w_hi.w;
        __syncthreads();
        #pragma unroll
        for (int k = 0; k < 64; k += 4) {
            const float4 a0 = *(const float4*)&As[ty][k];
            const float4 a1 = *(const float4*)&As[ty + 16][k];
            const float4 b0 = *(const float4*)&Bs[tx][k];
            const float4 b1 = *(const float4*)&Bs[tx + 16][k];
            acc00 += a0.x*b0.x; acc00 += a0.y*b0.y; acc00 += a0.z*b0.z; acc00 += a0.w*b0.w;
            acc01 += a0.x*b1.x; acc01 += a0.y*b1.y; acc01 += a0.z*b1.z; acc01 += a0.w*b1.w;
            acc10 += a1.x*b0.x; acc10 += a1.y*b0.y; acc10 += a1.z*b0.z; acc10 += a1.w*b0.w;
            acc11 += a1.x*b1.x; acc11 += a1.y*b1.y; acc11 += a1.z*b1.z; acc11 += a1.w*b1.w;
        }
    }

    out[(m0 + ty)      * YD + n0 + tx]      = acc00;
    out[(m0 + ty)      * YD + n0 + tx + 16] = acc01;
    out[(m0 + ty + 16) * YD + n0 + tx]      = acc10;
    out[(m0 + ty + 16) * YD + n0 + tx + 16] = acc11;
}

// ---------------------------------------------------------------------------
// reduce: per element e=(i,d):
//   mu  = sum_kz part_mu + b2_mu[d]
//   lv  = tanh(sum_kz part_lv + b2_lv[d]);  iv = exp(-lv)
//   pos += -0.5*(mu-y)^2*iv - 0.5*lv
//   ap  += iv*(-0.5*Sy2[d] + mu*Sy[d] - 0.5*B*mu^2) - 0.5*B*lv
// fp32 elementwise, fp64 accumulation + fp64 atomics.
// ---------------------------------------------------------------------------
__global__ __launch_bounds__(256) void reduce_kernel(
    const float* __restrict__ part, const float* __restrict__ y,
    const float* __restrict__ b2_mu, const float* __restrict__ b2_lv,
    const double* __restrict__ Sy, const double* __restrict__ Sy2,
    double* __restrict__ accum)
{
    const int NE = BSZ * YD;
    double pos = 0.0, ap = 0.0;
    for (int e = blockIdx.x * 256 + threadIdx.x; e < NE; e += 128 * 256) {
        const int d = e & (YD - 1);
        const float mu = part[0 * NE + e] + part[1 * NE + e]
                       + part[2 * NE + e] + part[3 * NE + e] + b2_mu[d];
        const float lvp = part[4 * NE + e] + part[5 * NE + e]
                        + part[6 * NE + e] + part[7 * NE + e] + b2_lv[d];
        const float lv = tanhf(lvp);
        const float iv = expf(-lv);
        const float dm = mu - y[e];
        pos += -0.5 * (double)dm * (double)dm * (double)iv - 0.5 * (double)lv;
        ap  += (double)iv * (-0.5 * Sy2[d] + (double)mu * Sy[d]
                             - 0.5 * (double)BSZ * (double)mu * (double)mu)
             - 0.5 * (double)BSZ * (double)lv;
    }
    #pragma unroll
    for (int off = 32; off > 0; off >>= 1) {
        pos += __shfl_down(pos, off);
        ap  += __shfl_down(ap, off);
    }
    __shared__ double sp[4];
    __shared__ double sa[4];
    const int lane = threadIdx.x & 63;
    const int wv   = threadIdx.x >> 6;
    if (lane == 0) { sp[wv] = pos; sa[wv] = ap; }
    __syncthreads();
    if (threadIdx.x == 0) {
        atomicAdd(&accum[0], sp[0] + sp[1] + sp[2] + sp[3]);
        atomicAdd(&accum[1], sa[0] + sa[1] + sa[2] + sa[3]);
    }
}

// ---------------------------------------------------------------------------
// finalize: out = posSum/B - apSum/B^2 - log1p(exp(-20)/(B-1))
// ---------------------------------------------------------------------------
__global__ void finalize_kernel(const double* __restrict__ accum,
                                float* __restrict__ out)
{
    if (threadIdx.x == 0) {
        const double C = log1p(exp(-20.0) / (double)(BSZ - 1));
        out[0] = (float)(accum[0] / (double)BSZ
                       - accum[1] / ((double)BSZ * (double)BSZ) - C);
    }
}

extern "C" void kernel_launch(void* const* d_in, const int* in_sizes, int n_in,
                              void* d_out, int out_size, void* d_ws, size_t ws_size,
                              hipStream_t stream) {
    const float* x     = (const float*)d_in[0];
    const float* y     = (const float*)d_in[1];
    const float* w1_mu = (const float*)d_in[2];
    const float* b1_mu = (const float*)d_in[3];
    const float* w2_mu = (const float*)d_in[4];
    const float* b2_mu = (const float*)d_in[5];
    const float* w1_lv = (const float*)d_in[6];
    const float* b1_lv = (const float*)d_in[7];
    const float* w2_lv = (const float*)d_in[8];
    const float* b2_lv = (const float*)d_in[9];

    char* ws = (char*)d_ws;
    float*  h_mu  = (float*)(ws);                                    // 1 MB
    float*  h_lv  = (float*)(ws + (size_t)BSZ * H2D * 4);            // 1 MB
    float*  part  = (float*)(ws + (size_t)2 * BSZ * H2D * 4);        // 2 MB (8 slices)
    double* Sy    = (double*)(ws + (size_t)2 * BSZ * H2D * 4
                                 + (size_t)8 * BSZ * YD * 4);        // 1 KB
    double* Sy2   = Sy + YD;                                         // 1 KB
    double* accum = Sy2 + YD;                                        // 16 B

    ysum_kernel<<<4, 512, 0, stream>>>(y, Sy, Sy2, accum);
    layer1_kernel<<<dim3(16, 16, 2), 256, 0, stream>>>(
        x, w1_mu, b1_mu, w1_lv, b1_lv, h_mu, h_lv);
    layer2p_kernel<<<dim3(16, 4, 8), 256, 0, stream>>>(
        h_mu, h_lv, w2_mu, w2_lv, part);
    reduce_kernel<<<128, 256, 0, stream>>>(
        part, y, b2_mu, b2_lv, Sy, Sy2, accum);
    finalize_kernel<<<1, 64, 0, stream>>>(accum, (float*)d_out);
}

// Round 3
// 109.645 us; speedup vs baseline: 1.4096x; 1.0728x over previous
//
#include <hip/hip_runtime.h>
#include <math.h>

// Problem constants
#define BSZ   512
#define XD    768
#define YD    128
#define H2D   512

// ---------------------------------------------------------------------------
// layer1: partials of x @ W1 (both branches, split-K x2). NO bias/relu here —
// applied during layer2's A-staging.
//   x:(512,768), W1:(768,512). p1[branch*2+ks][512][512], K-chunk 384.
// Tile 64x64, 4x4 per thread (2 FMA per LDS float), K-tile 16.
// Grid (8,8,5): z<4 = GEMM (branch=z>>1, ks=z&1) -> 256 blocks, 1/CU.
//               z==4 = ysum plane: 16 working blocks compute Sy/Sy2 columns
//               of y and zero the fp64 accumulators + finalize counter.
// Software prefetch: next tile's global loads issue before the FMA block.
// LDS: As[k][m] stride 68 (transposed scatter, 2-way = free),
//      Bs[k][n] stride 68 (direct float4 store, structural-peak 8 cyc).
// ---------------------------------------------------------------------------
__global__ __launch_bounds__(256, 2) void layer1_kernel(
    const float* __restrict__ x,
    const float* __restrict__ w1_mu, const float* __restrict__ w1_lv,
    const float* __restrict__ y,
    float* __restrict__ p1,
    double* __restrict__ Sy, double* __restrict__ Sy2,
    double* __restrict__ accum, unsigned int* __restrict__ counter)
{
    __shared__ float As[16][68];
    __shared__ float Bs[16][68];
    const int t = threadIdx.x;

    if (blockIdx.z == 4) {
        // ----- ysum plane: Sy[d], Sy2[d] + accumulator init -----
        const int id = blockIdx.x + 8 * blockIdx.y;
        if (id >= 16) return;
        const int dl = t & 7;
        const int g  = t >> 3;                  // 32 row-groups of 16
        const int d  = id * 8 + dl;
        float s = 0.f, s2 = 0.f;
        for (int i = g * 16; i < g * 16 + 16; ++i) {
            const float v = y[i * YD + d];
            s += v; s2 += v * v;
        }
        float* shs  = &As[0][0];                // reuse GEMM LDS
        float* shs2 = &Bs[0][0];
        shs[t] = s; shs2[t] = s2;
        __syncthreads();
        if (t < 8) {
            double S = 0.0, S2 = 0.0;
            #pragma unroll
            for (int gg = 0; gg < 32; ++gg) {
                S += (double)shs[gg * 8 + t]; S2 += (double)shs2[gg * 8 + t];
            }
            Sy[id * 8 + t] = S; Sy2[id * 8 + t] = S2;
        } else if (id == 0 && t == 8)  { accum[0] = 0.0; }
        else if (id == 0 && t == 9)  { accum[1] = 0.0; }
        else if (id == 0 && t == 10) { *counter = 0u; }
        return;
    }

    // ----- GEMM planes -----
    const int bz     = blockIdx.z;              // 0..3
    const int branch = bz >> 1;
    const int ks     = bz & 1;
    const float* __restrict__ W = branch ? w1_lv : w1_mu;
    float* __restrict__ out = p1 + (size_t)bz * (BSZ * H2D);

    const int m0 = blockIdx.x * 64;
    const int n0 = blockIdx.y * 64;
    const int tx = t & 15;
    const int ty = t >> 4;

    // staging maps: A 64m x 16k (1 float4/thread), B 16k x 64n (1 float4/thread)
    const int am  = t >> 2;                     // 0..63
    const int akq = (t & 3) << 2;               // 0,4,8,12
    const int bkk = t >> 4;                     // 0..15
    const int bnq = (t & 15) << 2;              // 0..60

    const int kbase = ks * 384;
    float acc[4][4] = {};

    float4 a_pref = *(const float4*)&x[(m0 + am) * XD + kbase + akq];
    float4 b_pref = *(const float4*)&W[(kbase + bkk) * H2D + n0 + bnq];

    for (int kt = 0; kt < 384; kt += 16) {
        __syncthreads();                        // LDS readers of prev tile done
        As[akq + 0][am] = a_pref.x;
        As[akq + 1][am] = a_pref.y;
        As[akq + 2][am] = a_pref.z;
        As[akq + 3][am] = a_pref.w;
        *(float4*)&Bs[bkk][bnq] = b_pref;
        __syncthreads();
        if (kt + 16 < 384) {                    // prefetch next tile (hides
            const int kn = kbase + kt + 16;     //  global latency under FMAs)
            a_pref = *(const float4*)&x[(m0 + am) * XD + kn + akq];
            b_pref = *(const float4*)&W[(kn + bkk) * H2D + n0 + bnq];
        }
        #pragma unroll
        for (int k = 0; k < 16; ++k) {
            const float4 av = *(const float4*)&As[k][ty * 4];
            const float4 bv = *(const float4*)&Bs[k][tx * 4];
            acc[0][0] += av.x*bv.x; acc[0][1] += av.x*bv.y; acc[0][2] += av.x*bv.z; acc[0][3] += av.x*bv.w;
            acc[1][0] += av.y*bv.x; acc[1][1] += av.y*bv.y; acc[1][2] += av.y*bv.z; acc[1][3] += av.y*bv.w;
            acc[2][0] += av.z*bv.x; acc[2][1] += av.z*bv.y; acc[2][2] += av.z*bv.z; acc[2][3] += av.z*bv.w;
            acc[3][0] += av.w*bv.x; acc[3][1] += av.w*bv.y; acc[3][2] += av.w*bv.z; acc[3][3] += av.w*bv.w;
        }
    }

    #pragma unroll
    for (int i = 0; i < 4; ++i) {
        const float4 o = make_float4(acc[i][0], acc[i][1], acc[i][2], acc[i][3]);
        *(float4*)&out[(m0 + ty * 4 + i) * H2D + n0 + tx * 4] = o;
    }
}

// ---------------------------------------------------------------------------
// layer2: partials of relu(p1a+p1b+b1) @ W2, split-K x8, both branches.
// H recomputed on the fly during A-staging (adds bias, relu). No b2/tanh here.
// H:(512,512), W2:(512,128). Grid (8,2,16): z = branch*8 + ks, K-chunk 64.
// p2[z][512][128]. Same tile template as layer1.
// ---------------------------------------------------------------------------
__global__ __launch_bounds__(256, 2) void layer2_kernel(
    const float* __restrict__ p1,
    const float* __restrict__ b1_mu, const float* __restrict__ b1_lv,
    const float* __restrict__ w2_mu, const float* __restrict__ w2_lv,
    float* __restrict__ p2)
{
    __shared__ float As[16][68];
    __shared__ float Bs[16][68];
    const int t = threadIdx.x;

    const int branch = blockIdx.z >> 3;
    const int ks     = blockIdx.z & 7;
    const float* __restrict__ pa = p1 + (size_t)(branch * 2 + 0) * (BSZ * H2D);
    const float* __restrict__ pb = p1 + (size_t)(branch * 2 + 1) * (BSZ * H2D);
    const float* __restrict__ b1 = branch ? b1_lv : b1_mu;
    const float* __restrict__ W  = branch ? w2_lv : w2_mu;
    float* __restrict__ out = p2 + (size_t)blockIdx.z * (BSZ * YD);

    const int m0 = blockIdx.x * 64;
    const int n0 = blockIdx.y * 64;
    const int tx = t & 15;
    const int ty = t >> 4;

    const int am  = t >> 2;
    const int akq = (t & 3) << 2;
    const int bkk = t >> 4;
    const int bnq = (t & 15) << 2;

    const int kbase = ks * 64;
    float acc[4][4] = {};

    float4 pa4 = *(const float4*)&pa[(m0 + am) * H2D + kbase + akq];
    float4 pb4 = *(const float4*)&pb[(m0 + am) * H2D + kbase + akq];
    float4 bb4 = *(const float4*)&b1[kbase + akq];
    float4 w4  = *(const float4*)&W[(kbase + bkk) * YD + n0 + bnq];

    for (int kt = 0; kt < 64; kt += 16) {
        __syncthreads();
        As[akq + 0][am] = fmaxf(pa4.x + pb4.x + bb4.x, 0.f);
        As[akq + 1][am] = fmaxf(pa4.y + pb4.y + bb4.y, 0.f);
        As[akq + 2][am] = fmaxf(pa4.z + pb4.z + bb4.z, 0.f);
        As[akq + 3][am] = fmaxf(pa4.w + pb4.w + bb4.w, 0.f);
        *(float4*)&Bs[bkk][bnq] = w4;
        __syncthreads();
        if (kt + 16 < 64) {
            const int kn = kbase + kt + 16;
            pa4 = *(const float4*)&pa[(m0 + am) * H2D + kn + akq];
            pb4 = *(const float4*)&pb[(m0 + am) * H2D + kn + akq];
            bb4 = *(const float4*)&b1[kn + akq];
            w4  = *(const float4*)&W[(kn + bkk) * YD + n0 + bnq];
        }
        #pragma unroll
        for (int k = 0; k < 16; ++k) {
            const float4 av = *(const float4*)&As[k][ty * 4];
            const float4 bv = *(const float4*)&Bs[k][tx * 4];
            acc[0][0] += av.x*bv.x; acc[0][1] += av.x*bv.y; acc[0][2] += av.x*bv.z; acc[0][3] += av.x*bv.w;
            acc[1][0] += av.y*bv.x; acc[1][1] += av.y*bv.y; acc[1][2] += av.y*bv.z; acc[1][3] += av.y*bv.w;
            acc[2][0] += av.z*bv.x; acc[2][1] += av.z*bv.y; acc[2][2] += av.z*bv.z; acc[2][3] += av.z*bv.w;
            acc[3][0] += av.w*bv.x; acc[3][1] += av.w*bv.y; acc[3][2] += av.w*bv.z; acc[3][3] += av.w*bv.w;
        }
    }

    #pragma unroll
    for (int i = 0; i < 4; ++i) {
        const float4 o = make_float4(acc[i][0], acc[i][1], acc[i][2], acc[i][3]);
        *(float4*)&out[(m0 + ty * 4 + i) * YD + n0 + tx * 4] = o;
    }
}

// ---------------------------------------------------------------------------
// reduce (+inline finalize): per element e=(i,d):
//   mu = sum_s p2[s][e] + b2_mu[d];  lv = tanh(sum_s p2[8+s][e] + b2_lv[d])
//   iv = exp(-lv)
//   pos += -0.5*(mu-y)^2*iv - 0.5*lv
//   ap  += iv*(-0.5*Sy2[d] + mu*Sy[d] - 256*mu^2) - 256*lv
// fp32 elementwise, fp64 block reduction + device atomics. The LAST block
// (atomic counter) reads back the totals and writes the scalar output.
// ---------------------------------------------------------------------------
__global__ __launch_bounds__(256) void reduce_kernel(
    const float* __restrict__ p2, const float* __restrict__ y,
    const float* __restrict__ b2_mu, const float* __restrict__ b2_lv,
    const double* __restrict__ Sy, const double* __restrict__ Sy2,
    double* __restrict__ accum, unsigned int* __restrict__ counter,
    float* __restrict__ outp)
{
    const int NE = BSZ * YD;
    const int e  = blockIdx.x * 256 + threadIdx.x;   // grid 256 covers exactly
    const int d  = e & (YD - 1);

    float mu = b2_mu[d];
    float lp = b2_lv[d];
    #pragma unroll
    for (int s = 0; s < 8; ++s) {
        mu += p2[s * NE + e];
        lp += p2[(8 + s) * NE + e];
    }
    const float lv = tanhf(lp);
    const float iv = expf(-lv);
    const float dm = mu - y[e];

    double pos = -0.5 * (double)dm * (double)dm * (double)iv - 0.5 * (double)lv;
    double ap  = (double)iv * (-0.5 * Sy2[d] + (double)mu * Sy[d]
                               - 256.0 * (double)mu * (double)mu)
               - 256.0 * (double)lv;

    #pragma unroll
    for (int off = 32; off > 0; off >>= 1) {
        pos += __shfl_down(pos, off);
        ap  += __shfl_down(ap, off);
    }
    __shared__ double sp[4];
    __shared__ double sa[4];
    const int lane = threadIdx.x & 63;
    const int wv   = threadIdx.x >> 6;
    if (lane == 0) { sp[wv] = pos; sa[wv] = ap; }
    __syncthreads();
    if (threadIdx.x == 0) {
        atomicAdd(&accum[0], sp[0] + sp[1] + sp[2] + sp[3]);
        atomicAdd(&accum[1], sa[0] + sa[1] + sa[2] + sa[3]);
        __threadfence();
        const unsigned int old = atomicAdd(counter, 1u);
        if (old == 255u) {                 // last block: finalize
            const double P = atomicAdd(&accum[0], 0.0);   // coherent read-back
            const double A = atomicAdd(&accum[1], 0.0);
            const double C = log1p(exp(-20.0) / 511.0);
            outp[0] = (float)(P / 512.0 - A / 262144.0 - C);
        }
    }
}

extern "C" void kernel_launch(void* const* d_in, const int* in_sizes, int n_in,
                              void* d_out, int out_size, void* d_ws, size_t ws_size,
                              hipStream_t stream) {
    const float* x     = (const float*)d_in[0];
    const float* y     = (const float*)d_in[1];
    const float* w1_mu = (const float*)d_in[2];
    const float* b1_mu = (const float*)d_in[3];
    const float* w2_mu = (const float*)d_in[4];
    const float* b2_mu = (const float*)d_in[5];
    const float* w1_lv = (const float*)d_in[6];
    const float* b1_lv = (const float*)d_in[7];
    const float* w2_lv = (const float*)d_in[8];
    const float* b2_lv = (const float*)d_in[9];

    char* ws = (char*)d_ws;
    float*  p1 = (float*)(ws);                                     // 4 MB
    float*  p2 = (float*)(ws + (size_t)4 * BSZ * H2D * 4);         // 4 MB
    double* Sy = (double*)(ws + (size_t)4 * BSZ * H2D * 4
                              + (size_t)16 * BSZ * YD * 4);        // 1 KB
    double* Sy2 = Sy + YD;                                         // 1 KB
    double* accum = Sy2 + YD;                                      // 16 B
    unsigned int* counter = (unsigned int*)(accum + 2);            // 4 B

    layer1_kernel<<<dim3(8, 8, 5), 256, 0, stream>>>(
        x, w1_mu, w1_lv, y, p1, Sy, Sy2, accum, counter);
    layer2_kernel<<<dim3(8, 2, 16), 256, 0, stream>>>(
        p1, b1_mu, b1_lv, w2_mu, w2_lv, p2);
    reduce_kernel<<<256, 256, 0, stream>>>(
        p2, y, b2_mu, b2_lv, Sy, Sy2, accum, counter, (float*)d_out);
}